// Round 10
// baseline (250.424 us; speedup 1.0000x reference)
//
#include <hip/hip_runtime.h>

// Problem constants (fixed by the reference)
constexpr int C_ = 2048;
constexpr int H_ = 16;
constexpr int W_ = 16;
constexpr int F_ = 64;
constexpr int P_ = 256;               // samples per complex
constexpr int CHUNK = 16;             // samples per block
constexpr int NB = C_ * (P_ / CHUNK); // 32768 blocks

// Round-7 conclusion: seven synchronized-heavyweight-block structures all pin
// at 2.4-2.7 TB/s (82-86us) with every on-CU resource idle; the harness's own
// fillBuffer (tens of thousands of tiny independent blocks, no LDS, no
// barriers) hits 6.7 TB/s on the same machine. The best prior rate (2.7) came
// from the one barrier-free gather variant. So: make the kernel fill-shaped.
//   - 32768 independent 256-thread blocks, ZERO LDS, ZERO syncthreads.
//   - block (c, k): 16 samples of complex c. XCD-aware mapping puts all 16
//     blocks of a complex on ONE XCD consecutively -> map tile fetched into
//     that XCD's L2 once, hit 15x (fixes round-1's 2.2x HBM over-fetch).
//   - 16 lanes per sample compute coeffs redundantly in-register (VALU is at
//     5%; redundancy is free). 4 independent 256B-segment gathers per group.
//   - stores: 16-lane group writes 256B contiguous; wave writes 1KB.
//   - 128 blocks/CU queued; __launch_bounds__(256,8) -> VGPR<=64, 32 waves/CU.
// (Round-9 resubmit: round-9 bench was an infra double-failure -- this kernel
//  has no barriers/asm/cross-block deps, no hang mode. Theory unchanged.)

__global__ __launch_bounds__(256, 8) void ngf_fetch_kernel(
    const float* __restrict__ map_,
    const float* __restrict__ u_,
    const float* __restrict__ v_,
    float* __restrict__ out_) {
  const int b = blockIdx.x;
  // XCD-aware decode: blocks round-robin XCDs by b%8. Give XCD x complexes
  // [x*256, (x+1)*256); the 16 chunk-blocks of a complex are consecutive
  // slots on that XCD, so its 64KB map tile stays L2-hot while they run.
  const int xcd  = b & 7;
  const int slot = b >> 3;              // 0..4095 within this XCD
  const int c    = (xcd << 8) | (slot >> 4);  // complex 0..2047
  const int k    = slot & 15;           // chunk within complex

  const int tid = threadIdx.x;
  const int f = tid & 15;               // float4 index along features (0..15)
  const int s = (k << 4) | (tid >> 4);  // sample index 0..255

  // ---- per-sample coeffs, computed redundantly by the 16 lanes ----
  const float x = u_[(size_t)c * P_ + s] * (float)(W_ - 1);
  const float y = v_[(size_t)c * P_ + s] * (float)(H_ - 1);
  int x0 = (int)floorf(x);
  int y0 = (int)floorf(y);
  x0 = x0 < 0 ? 0 : (x0 > W_ - 2 ? W_ - 2 : x0);
  y0 = y0 < 0 ? 0 : (y0 > H_ - 2 ? H_ - 2 : y0);
  const float wx1 = x - (float)x0, wx0 = 1.0f - wx1;
  const float wy1 = y - (float)y0, wy0 = 1.0f - wy1;

  // ---- 4 independent gathers (256B segment per 16-lane group each) ----
  const float4* __restrict__ gmap =
      (const float4*)(map_ + (size_t)c * (H_ * W_ * F_));
  const int ix = (y0 * W_ + x0) * (F_ / 4) + f;

  const float4 g00 = gmap[ix];
  const float4 g01 = gmap[ix + (F_ / 4)];            // x0+1
  const float4 g10 = gmap[ix + W_ * (F_ / 4)];       // y0+1
  const float4 g11 = gmap[ix + (W_ + 1) * (F_ / 4)]; // y0+1, x0+1

  float4 r;
  r.x = (g00.x * wx0 + g01.x * wx1) * wy0 + (g10.x * wx0 + g11.x * wx1) * wy1;
  r.y = (g00.y * wx0 + g01.y * wx1) * wy0 + (g10.y * wx0 + g11.y * wx1) * wy1;
  r.z = (g00.z * wx0 + g01.z * wx1) * wy0 + (g10.z * wx0 + g11.z * wx1) * wy1;
  r.w = (g00.w * wx0 + g01.w * wx1) * wy0 + (g10.w * wx0 + g11.w * wx1) * wy1;

  // ---- store: group writes 256B contiguous, wave writes 1KB ----
  float4* __restrict__ gout = (float4*)(out_ + (size_t)c * (P_ * F_));
  gout[s * (F_ / 4) + f] = r;
}

extern "C" void kernel_launch(void* const* d_in, const int* in_sizes, int n_in,
                              void* d_out, int out_size, void* d_ws, size_t ws_size,
                              hipStream_t stream) {
  const float* map_ = (const float*)d_in[0];
  const float* u_   = (const float*)d_in[1];
  const float* v_   = (const float*)d_in[2];
  float* out_ = (float*)d_out;

  ngf_fetch_kernel<<<NB, 256, 0, stream>>>(map_, u_, v_, out_);
}

// Round 12
// 250.056 us; speedup vs baseline: 1.0015x; 1.0015x over previous
//
#include <hip/hip_runtime.h>

// Problem constants (fixed by the reference)
constexpr int C_ = 2048;
constexpr int H_ = 16;
constexpr int W_ = 16;
constexpr int F_ = 64;
constexpr int P_ = 256;               // samples per complex
constexpr int NB = 2048;              // 8 blocks/CU, ALL co-resident

// Round-11 lessons: (a) sc0/sc1/nt stores break coherence with the
// verification read (stale memset zeros in L2) -- plain stores only.
// (b) R10 (fill-shaped, 32768 tiny blocks) pinned at 2.2 TB/s HBM but the
// memory SYSTEM moved ~7.1 TB/s (512MB L2/L3-served gathers + stores); its
// untested defect: 128 sequential block-turnarounds per CU, each one bare
// dependent load->store chain -- no per-thread pipelining, per-KB teardown.
// This round: PERSISTENT gather. Same independence (no LDS, no barriers),
// but 2048 co-resident blocks x 16-step unrolled loop, u/v software-
// prefetched one step ahead, so every thread continuously has independent
// gathers + stores in flight (fill-loop shape, legal semantics).
// XCD locality: block b -> xcd=b&7; the 16 blocks of subgroup grp share
// complex (xcd*256 + j*16 + grp) at step j; XCD L2 (64 maps) absorbs drift.

__global__ __launch_bounds__(256, 8) void ngf_fetch_kernel(
    const float* __restrict__ map_,
    const float* __restrict__ u_,
    const float* __restrict__ v_,
    float* __restrict__ out_) {
  const int b   = blockIdx.x;
  const int xcd = b & 7;               // empirically blockIdx%8 = XCD
  const int lb  = b >> 3;              // 0..255 local block on this XCD
  const int grp = lb >> 4;             // 0..15: complex subgroup
  const int k   = lb & 15;             // chunk of 16 samples
  const int tid = threadIdx.x;
  const int f   = tid & 15;            // float4 index along features
  const int s   = (k << 4) | (tid >> 4);  // sample 0..255 (fixed per block)

  // step j handles complex c = xcd*256 + j*16 + grp  (j = 0..15)
  const int cbase = (xcd << 8) | grp;

  // ---- software-pipelined u/v: load step j+1 while gathering step j ----
  float u = u_[(size_t)cbase * P_ + s];
  float v = v_[(size_t)cbase * P_ + s];

#pragma unroll
  for (int j = 0; j < 16; ++j) {
    const int c = cbase + (j << 4);

    float un = 0.0f, vn = 0.0f;
    if (j < 15) {                       // prefetch next step's u,v
      const size_t nofs = (size_t)(c + 16) * P_ + s;
      un = u_[nofs];
      vn = v_[nofs];
    }

    // per-sample coeffs (redundant across the 16 lanes of the group)
    const float x = u * (float)(W_ - 1);
    const float y = v * (float)(H_ - 1);
    int x0 = (int)floorf(x);
    int y0 = (int)floorf(y);
    x0 = x0 < 0 ? 0 : (x0 > W_ - 2 ? W_ - 2 : x0);
    y0 = y0 < 0 ? 0 : (y0 > H_ - 2 ? H_ - 2 : y0);
    const float wx1 = x - (float)x0, wx0 = 1.0f - wx1;
    const float wy1 = y - (float)y0, wy0 = 1.0f - wy1;

    // 4 independent 256B-segment gathers (16-lane group each)
    const float4* __restrict__ gmap =
        (const float4*)(map_ + (size_t)c * (H_ * W_ * F_));
    const int ix = (y0 * W_ + x0) * (F_ / 4) + f;

    const float4 g00 = gmap[ix];
    const float4 g01 = gmap[ix + (F_ / 4)];            // x0+1
    const float4 g10 = gmap[ix + W_ * (F_ / 4)];       // y0+1
    const float4 g11 = gmap[ix + (W_ + 1) * (F_ / 4)]; // y0+1, x0+1

    float4 r;
    r.x = (g00.x * wx0 + g01.x * wx1) * wy0 + (g10.x * wx0 + g11.x * wx1) * wy1;
    r.y = (g00.y * wx0 + g01.y * wx1) * wy0 + (g10.y * wx0 + g11.y * wx1) * wy1;
    r.z = (g00.z * wx0 + g01.z * wx1) * wy0 + (g10.z * wx0 + g11.z * wx1) * wy1;
    r.w = (g00.w * wx0 + g01.w * wx1) * wy0 + (g10.w * wx0 + g11.w * wx1) * wy1;

    // plain coherent store: 16-lane group writes 256B, wave writes 1KB
    float4* __restrict__ gout = (float4*)(out_ + (size_t)c * (P_ * F_));
    gout[s * (F_ / 4) + f] = r;

    u = un;
    v = vn;
  }
}

extern "C" void kernel_launch(void* const* d_in, const int* in_sizes, int n_in,
                              void* d_out, int out_size, void* d_ws, size_t ws_size,
                              hipStream_t stream) {
  const float* map_ = (const float*)d_in[0];
  const float* u_   = (const float*)d_in[1];
  const float* v_   = (const float*)d_in[2];
  float* out_ = (float*)d_out;

  ngf_fetch_kernel<<<NB, 256, 0, stream>>>(map_, u_, v_, out_);
}